// Round 1
// baseline (41.549 us; speedup 1.0000x reference)
//
#include <hip/hip_runtime.h>

// DifferentiableJPEG forward on MI355X.
// One thread processes one 8x8 block fully in registers:
//   load -> (x-0.5) -> D@X@D^T -> round(./q)*q -> D^T@Y@D -> clip(x+0.5,0,1) -> store
// Memory-bound: ~200MB traffic, floor ~32us @ 6.3TB/s.

static __device__ __constant__ float c_qbase[64] = {
    16.f, 11.f, 10.f, 16.f, 24.f, 40.f, 51.f, 61.f,
    12.f, 12.f, 14.f, 19.f, 26.f, 58.f, 60.f, 55.f,
    14.f, 13.f, 16.f, 24.f, 40.f, 57.f, 69.f, 56.f,
    14.f, 17.f, 22.f, 29.f, 51.f, 87.f, 80.f, 62.f,
    18.f, 22.f, 37.f, 56.f, 68.f, 109.f, 103.f, 77.f,
    24.f, 35.f, 55.f, 64.f, 81.f, 104.f, 113.f, 92.f,
    49.f, 64.f, 78.f, 87.f, 103.f, 121.f, 120.f, 101.f,
    72.f, 92.f, 95.f, 98.f, 112.f, 100.f, 103.f, 99.f
};

__global__ __launch_bounds__(256, 2)
void jpeg_fused_kernel(const float* __restrict__ in, const int* __restrict__ qual,
                       float* __restrict__ out, int nblk, int W) {
    // Orthonormal 8x8 DCT-II basis, fp32-rounded from double (matches reference).
    constexpr float D[8][8] = {
        { 0.3535533906f,  0.3535533906f,  0.3535533906f,  0.3535533906f,
          0.3535533906f,  0.3535533906f,  0.3535533906f,  0.3535533906f },
        { 0.4903926402f,  0.4157348062f,  0.2777851165f,  0.0975451610f,
         -0.0975451610f, -0.2777851165f, -0.4157348062f, -0.4903926402f },
        { 0.4619397663f,  0.1913417162f, -0.1913417162f, -0.4619397663f,
         -0.4619397663f, -0.1913417162f,  0.1913417162f,  0.4619397663f },
        { 0.4157348062f, -0.0975451610f, -0.4903926402f, -0.2777851165f,
          0.2777851165f,  0.4903926402f,  0.0975451610f, -0.4157348062f },
        { 0.3535533906f, -0.3535533906f, -0.3535533906f,  0.3535533906f,
          0.3535533906f, -0.3535533906f, -0.3535533906f,  0.3535533906f },
        { 0.2777851165f, -0.4903926402f,  0.0975451610f,  0.4157348062f,
         -0.4157348062f, -0.0975451610f,  0.4903926402f, -0.2777851165f },
        { 0.1913417162f, -0.4619397663f,  0.4619397663f, -0.1913417162f,
         -0.1913417162f,  0.4619397663f, -0.4619397663f,  0.1913417162f },
        { 0.0975451610f, -0.2777851165f,  0.4157348062f, -0.4903926402f,
          0.4903926402f, -0.4157348062f,  0.2777851165f, -0.0975451610f }
    };

    // Build quant table once per workgroup in LDS (reads are wave-uniform -> broadcast).
    __shared__ float qlds[64];
    if (threadIdx.x < 64) {
        int q = qual[0];
        double sd = (q < 50) ? (5000.0 / (double)q) : (200.0 - 2.0 * (double)q);
        float scale = (float)sd;                       // JAX weak-type python float -> f32
        float v = c_qbase[threadIdx.x] * scale / 100.0f;
        qlds[threadIdx.x] = fminf(fmaxf(v, 1.0f), 255.0f);
    }
    __syncthreads();

    int t = blockIdx.x * 256 + threadIdx.x;            // one thread = one 8x8 block
    if (t >= nblk) return;

    const int img = t >> 12;                           // 64*64 blocks per 512x512 plane
    const int by  = (t >> 6) & 63;
    const int bx  = t & 63;
    const long base = ((long)img * 512 + (long)by * 8) * (long)W + (long)bx * 8;

    // Load block, subtract 0.5
    float X[8][8];
#pragma unroll
    for (int r = 0; r < 8; ++r) {
        const float4 a = *reinterpret_cast<const float4*>(in + base + (long)r * W);
        const float4 b = *reinterpret_cast<const float4*>(in + base + (long)r * W + 4);
        X[r][0] = a.x - 0.5f; X[r][1] = a.y - 0.5f; X[r][2] = a.z - 0.5f; X[r][3] = a.w - 0.5f;
        X[r][4] = b.x - 0.5f; X[r][5] = b.y - 0.5f; X[r][6] = b.z - 0.5f; X[r][7] = b.w - 0.5f;
    }

    // T = D @ X
    float T[8][8];
#pragma unroll
    for (int k = 0; k < 8; ++k) {
#pragma unroll
        for (int j = 0; j < 8; ++j) {
            float s = 0.0f;
#pragma unroll
            for (int i = 0; i < 8; ++i) s = fmaf(D[k][i], X[i][j], s);
            T[k][j] = s;
        }
    }

    // Per row k: Y = T @ D^T, quantize, then Z = Yq @ D back into T (X dead after this loop's first pass)
#pragma unroll
    for (int k = 0; k < 8; ++k) {
        float y[8];
#pragma unroll
        for (int l = 0; l < 8; ++l) {
            float s = 0.0f;
#pragma unroll
            for (int j = 0; j < 8; ++j) s = fmaf(T[k][j], D[l][j], s);
            const float qv = qlds[k * 8 + l];
            y[l] = rintf(s / qv) * qv;                 // IEEE div + half-even round, matches jnp
        }
#pragma unroll
        for (int j = 0; j < 8; ++j) {
            float s = 0.0f;
#pragma unroll
            for (int l = 0; l < 8; ++l) s = fmaf(y[l], D[l][j], s);
            T[k][j] = s;                               // T now holds Z = Yq @ D
        }
    }

    // S = D^T @ Z, +0.5, clip, stream out row by row
#pragma unroll
    for (int i = 0; i < 8; ++i) {
        float srow[8];
#pragma unroll
        for (int j = 0; j < 8; ++j) {
            float s = 0.0f;
#pragma unroll
            for (int k = 0; k < 8; ++k) s = fmaf(D[k][i], T[k][j], s);
            s += 0.5f;
            srow[j] = fminf(fmaxf(s, 0.0f), 1.0f);
        }
        float4 a = make_float4(srow[0], srow[1], srow[2], srow[3]);
        float4 b = make_float4(srow[4], srow[5], srow[6], srow[7]);
        *reinterpret_cast<float4*>(out + base + (long)i * W)     = a;
        *reinterpret_cast<float4*>(out + base + (long)i * W + 4) = b;
    }
}

extern "C" void kernel_launch(void* const* d_in, const int* in_sizes, int n_in,
                              void* d_out, int out_size, void* d_ws, size_t ws_size,
                              hipStream_t stream) {
    const float* img  = (const float*)d_in[0];
    const int*   qual = (const int*)d_in[1];
    float*       out  = (float*)d_out;

    const int W = 512;
    const int nblk = out_size / 64;                    // total 8x8 blocks = 393216
    const int nthreads = 256;
    const int ngrid = (nblk + nthreads - 1) / nthreads;

    jpeg_fused_kernel<<<ngrid, nthreads, 0, stream>>>(img, qual, out, nblk, W);
}

// Round 2
// 36.008 us; speedup vs baseline: 1.1539x; 1.1539x over previous
//
#include <hip/hip_runtime.h>

// DifferentiableJPEG forward on MI355X — round 2.
// 8 threads per 8x8 block (one per row) for 8x the wave parallelism.
// Column transforms via in-wave LDS transposes (padded stride, no barriers:
// each wave owns a private LDS slice; 8-lane exchange groups never span waves).

static __device__ __constant__ float c_qbase[64] = {
    16.f, 11.f, 10.f, 16.f, 24.f, 40.f, 51.f, 61.f,
    12.f, 12.f, 14.f, 19.f, 26.f, 58.f, 60.f, 55.f,
    14.f, 13.f, 16.f, 24.f, 40.f, 57.f, 69.f, 56.f,
    14.f, 17.f, 22.f, 29.f, 51.f, 87.f, 80.f, 62.f,
    18.f, 22.f, 37.f, 56.f, 68.f, 109.f, 103.f, 77.f,
    24.f, 35.f, 55.f, 64.f, 81.f, 104.f, 113.f, 92.f,
    49.f, 64.f, 78.f, 87.f, 103.f, 121.f, 120.f, 101.f,
    72.f, 92.f, 95.f, 98.f, 112.f, 100.f, 103.f, 99.f
};

#define LDS_PITCH 9  // +1 float pad: write bank = 9*t mod 32 (gcd(9,32)=1) -> 2-way max

__global__ __launch_bounds__(256, 8)
void jpeg_row_kernel(const float* __restrict__ in, const int* __restrict__ qual,
                     float* __restrict__ out) {
    constexpr float D[8][8] = {
        { 0.3535533906f,  0.3535533906f,  0.3535533906f,  0.3535533906f,
          0.3535533906f,  0.3535533906f,  0.3535533906f,  0.3535533906f },
        { 0.4903926402f,  0.4157348062f,  0.2777851165f,  0.0975451610f,
         -0.0975451610f, -0.2777851165f, -0.4157348062f, -0.4903926402f },
        { 0.4619397663f,  0.1913417162f, -0.1913417162f, -0.4619397663f,
         -0.4619397663f, -0.1913417162f,  0.1913417162f,  0.4619397663f },
        { 0.4157348062f, -0.0975451610f, -0.4903926402f, -0.2777851165f,
          0.2777851165f,  0.4903926402f,  0.0975451610f, -0.4157348062f },
        { 0.3535533906f, -0.3535533906f, -0.3535533906f,  0.3535533906f,
          0.3535533906f, -0.3535533906f, -0.3535533906f,  0.3535533906f },
        { 0.2777851165f, -0.4903926402f,  0.0975451610f,  0.4157348062f,
         -0.4157348062f, -0.0975451610f,  0.4903926402f, -0.2777851165f },
        { 0.1913417162f, -0.4619397663f,  0.4619397663f, -0.1913417162f,
         -0.1913417162f,  0.4619397663f, -0.4619397663f,  0.1913417162f },
        { 0.0975451610f, -0.2777851165f,  0.4157348062f, -0.4903926402f,
          0.4903926402f, -0.4157348062f,  0.2777851165f, -0.0975451610f }
    };

    __shared__ float qlds[64];
    __shared__ float tr[256 * LDS_PITCH];

    if (threadIdx.x < 64) {
        int q = qual[0];
        double sd = (q < 50) ? (5000.0 / (double)q) : (200.0 - 2.0 * (double)q);
        float scale = (float)sd;
        float v = c_qbase[threadIdx.x] * scale / 100.0f;
        qlds[threadIdx.x] = fminf(fmaxf(v, 1.0f), 255.0f);
    }
    __syncthreads();

    const int tid = threadIdx.x;
    const int gt  = blockIdx.x * 256 + tid;       // global (block,row) id
    const int b   = gt >> 3;                      // 8x8-block index
    const int r   = gt & 7;                       // row within block (also col after transpose)
    const int img = b >> 12;                      // 64*64 blocks per 512x512 plane
    const int by  = (b >> 6) & 63;
    const int bx  = b & 63;
    const long rowaddr = (((long)img * 512 + (long)by * 8 + r) * 512) + (long)bx * 8;

    // my quant column: q[k][r] for k=0..7 (lane holds column r during quantize)
    float qc[8];
#pragma unroll
    for (int k = 0; k < 8; ++k) qc[k] = qlds[k * 8 + r];

    // load row r, subtract 0.5
    float x[8];
    {
        const float4 a  = *reinterpret_cast<const float4*>(in + rowaddr);
        const float4 b4 = *reinterpret_cast<const float4*>(in + rowaddr + 4);
        x[0] = a.x - 0.5f; x[1] = a.y - 0.5f; x[2] = a.z - 0.5f; x[3] = a.w - 0.5f;
        x[4] = b4.x - 0.5f; x[5] = b4.y - 0.5f; x[6] = b4.z - 0.5f; x[7] = b4.w - 0.5f;
    }

    // Stage A: row transform  u[l] = (X D^T)[r][l]
    float u[8];
#pragma unroll
    for (int l = 0; l < 8; ++l) {
        float s = 0.0f;
#pragma unroll
        for (int j = 0; j < 8; ++j) s = fmaf(x[j], D[l][j], s);
        u[l] = s;
    }

    // Transpose 1 (wave-private LDS slice, no barrier needed)
    const int base_w = tid * LDS_PITCH;
    const int base_r = (tid & ~7) * LDS_PITCH;    // first row of my 8-lane group
#pragma unroll
    for (int j = 0; j < 8; ++j) tr[base_w + j] = u[j];
    float t[8];
#pragma unroll
    for (int j = 0; j < 8; ++j) t[j] = tr[base_r + j * LDS_PITCH + r];  // t[j] = U[j][r]

    // Stage B: column transform y[k] = (D U)[k][r] = Y[k][r]; then quantize
    float y[8];
#pragma unroll
    for (int k = 0; k < 8; ++k) {
        float s = 0.0f;
#pragma unroll
        for (int j = 0; j < 8; ++j) s = fmaf(D[k][j], t[j], s);
        y[k] = rintf(s / qc[k]) * qc[k];          // IEEE div + half-even round
    }

    // Stage C1: v[j] = (D^T Yq)[j][r]
    float v[8];
#pragma unroll
    for (int j = 0; j < 8; ++j) {
        float s = 0.0f;
#pragma unroll
        for (int k = 0; k < 8; ++k) s = fmaf(D[k][j], y[k], s);
        v[j] = s;
    }

    // Transpose 2 (same wave-private slice; in-wave program order keeps it safe)
#pragma unroll
    for (int j = 0; j < 8; ++j) tr[base_w + j] = v[j];
    float w[8];
#pragma unroll
    for (int j = 0; j < 8; ++j) w[j] = tr[base_r + j * LDS_PITCH + r];  // w[j] = V[r][j]

    // Stage C2: s[c] = (V D)[r][c], +0.5, clip, store
    float srow[8];
#pragma unroll
    for (int c = 0; c < 8; ++c) {
        float s = 0.0f;
#pragma unroll
        for (int l = 0; l < 8; ++l) s = fmaf(w[l], D[l][c], s);
        s += 0.5f;
        srow[c] = fminf(fmaxf(s, 0.0f), 1.0f);
    }
    *reinterpret_cast<float4*>(out + rowaddr)     = make_float4(srow[0], srow[1], srow[2], srow[3]);
    *reinterpret_cast<float4*>(out + rowaddr + 4) = make_float4(srow[4], srow[5], srow[6], srow[7]);
}

extern "C" void kernel_launch(void* const* d_in, const int* in_sizes, int n_in,
                              void* d_out, int out_size, void* d_ws, size_t ws_size,
                              hipStream_t stream) {
    const float* img  = (const float*)d_in[0];
    const int*   qual = (const int*)d_in[1];
    float*       out  = (float*)d_out;

    const int nthreads_total = (out_size / 64) * 8;   // 8 threads per 8x8 block
    const int block = 256;
    const int grid = nthreads_total / block;          // 12288 for 32x3x512x512

    jpeg_row_kernel<<<grid, block, 0, stream>>>(img, qual, out);
}